// Round 6
// baseline (32.971 us; speedup 1.0000x reference)
//
#include <hip/hip_runtime.h>

// Reference collapses: softmax over a singleton axis == 1, so the attention
// output is v broadcast over all N=4096 spatial positions:
//   out[b,c,:,:] = (Wout @ v_b + bout)[c],  v_b = Wkv[C:,:] @ context[b]
// x and Wq are dead inputs. Bound by the 134 MB output write.
//
// K1a/K1b: tiny wave-per-row GEMVs. K2: fill-shaped broadcast — few
// long-lived waves, 4 consecutive rows each, scalar y prefetch, dense
// store stream (the harness's own fill kernel hits 7 TB/s this way).

#define BB   16
#define CC   512
#define CTX  256
#define NN   4096   // H*W

typedef float f32x4 __attribute__((ext_vector_type(4)));

// K1a: v[b*C+j] = dot(Wkv[C+j,:], ctx[b,:]).  One wave per (b,j).
__global__ __launch_bounds__(256) void v_kernel(
    const float* __restrict__ ctx,   // B x CTX
    const float* __restrict__ Wkv,   // 2C x CTX
    float* __restrict__ v)           // B*C (d_ws)
{
    const int w    = (blockIdx.x << 2) + (threadIdx.x >> 6);  // 0..8191
    const int lane = threadIdx.x & 63;
    const int b    = w >> 9;          // /C
    const int j    = w & (CC - 1);

    const f32x4 cx = ((const f32x4*)(ctx + b * CTX))[lane];
    const f32x4 wv = ((const f32x4*)(Wkv + (size_t)(CC + j) * CTX))[lane];
    float p = wv.x * cx.x + wv.y * cx.y + wv.z * cx.z + wv.w * cx.w;
    #pragma unroll
    for (int m = 32; m >= 1; m >>= 1) p += __shfl_xor(p, m);
    if (lane == 0) v[w] = p;
}

// K1b: y[b*C+c] = dot(Wout[c,:], v[b,:]) + bout[c].  One wave per (b,c).
__global__ __launch_bounds__(256) void y_kernel(
    const float* __restrict__ v,     // B*C
    const float* __restrict__ Wout,  // C x C
    const float* __restrict__ bout,  // C
    float* __restrict__ y)           // B*C (d_ws)
{
    const int w    = (blockIdx.x << 2) + (threadIdx.x >> 6);
    const int lane = threadIdx.x & 63;
    const int b    = w >> 9;
    const int c    = w & (CC - 1);

    const f32x4* vr = (const f32x4*)(v + (size_t)b * CC);
    const f32x4* wr = (const f32x4*)(Wout + (size_t)c * CC);
    const f32x4 w0 = wr[lane],      v0 = vr[lane];
    const f32x4 w1 = wr[64 + lane], v1 = vr[64 + lane];
    float p = w0.x * v0.x + w0.y * v0.y + w0.z * v0.z + w0.w * v0.w
            + w1.x * v1.x + w1.y * v1.y + w1.z * v1.z + w1.w * v1.w;
    #pragma unroll
    for (int m = 32; m >= 1; m >>= 1) p += __shfl_xor(p, m);
    if (lane == 0) y[w] = p + bout[c];
}

// K2: broadcast, fill-kernel shape. 512 blocks x 256 threads = 2048 waves,
// each wave owns 4 CONSECUTIVE rows (64 KB contiguous): scalar-prefetch the
// 4 y values, then 64 back-to-back independent dwordx4 stores.
__global__ __launch_bounds__(256) void bcast_kernel(
    const float* __restrict__ y, f32x4* __restrict__ out)
{
    const int wave = (blockIdx.x << 2) + (threadIdx.x >> 6);  // 0..2047
    const int lane = threadIdx.x & 63;
    const int r0   = __builtin_amdgcn_readfirstlane(wave << 2);  // first of 4 rows

    float yv[4];
    #pragma unroll
    for (int i = 0; i < 4; ++i) yv[i] = y[r0 + i];   // uniform addr -> s_load

    #pragma unroll
    for (int i = 0; i < 4; ++i) {
        f32x4 val; val.x = yv[i]; val.y = yv[i]; val.z = yv[i]; val.w = yv[i];
        f32x4* dst = out + (size_t)(r0 + i) * (NN / 4) + lane;
        #pragma unroll
        for (int j = 0; j < 16; ++j)
            dst[j * 64] = val;
    }
}

extern "C" void kernel_launch(void* const* d_in, const int* in_sizes, int n_in,
                              void* d_out, int out_size, void* d_ws, size_t ws_size,
                              hipStream_t stream) {
    // inputs: 0=x (dead), 1=context, 2=Wq (dead), 3=Wkv, 4=Wout, 5=bout
    const float* context = (const float*)d_in[1];
    const float* Wkv     = (const float*)d_in[3];
    const float* Wout    = (const float*)d_in[4];
    const float* bout    = (const float*)d_in[5];
    float* out = (float*)d_out;
    float* y   = (float*)d_ws;              // B*C floats
    float* v   = (float*)d_ws + BB * CC;    // B*C floats

    v_kernel<<<(BB * CC) / 4, 256, 0, stream>>>(context, Wkv, v);
    y_kernel<<<(BB * CC) / 4, 256, 0, stream>>>(v, Wout, bout, y);
    bcast_kernel<<<512, 256, 0, stream>>>(y, (f32x4*)out);
}